// Round 5
// baseline (92.423 us; speedup 1.0000x reference)
//
#include <hip/hip_runtime.h>

// piecewise max-pool: conv [B, S=256, F=230] f32, positions [B,4] i32 -> out [B, 3*230] f32
// Per batch b: e1=pos[b][1], e2=pos[b][3]; max over s-ranges [0,e1), [e1,e2), [e2,S).
//
// R5: A/B vs R4 — drop nontemporal on the LOAD stream (let Infinity Cache retain
// up to 256 MB of the 482 MB input across graph replays; NT forced every line to
// HBM), and deepen unroll 4->8. Structure otherwise identical to R4:
// 4 rows = 920 floats = 3680 B (16B-aligned chunk stride); thread t owns flat slots
// [4t,4t+4) of every 4-row chunk -> all loads global_load_dwordx4, register
// accumulation across all 64 chunks; straddlers handled by per-element row offsets.

constexpr int S   = 256;
constexpr int Fn  = 230;
constexpr int RPC = 4;                 // rows per chunk
constexpr int CF  = Fn * RPC;          // 920 floats per chunk
constexpr int NCH = S / RPC;           // 64 chunks
constexpr int NT  = CF / 4;            // 230 active threads
constexpr float NEG = -1e30f;

typedef float f32x4 __attribute__((ext_vector_type(4)));

__global__ __launch_bounds__(256) void pmax_kernel(
    const float* __restrict__ conv,
    const int*   __restrict__ pos,
    float*       __restrict__ out)
{
    const int b = blockIdx.x;
    const int t = threadIdx.x;
    const int e1 = pos[b * 4 + 1];
    const int e2 = pos[b * 4 + 3];
    const float* base = conv + (size_t)b * (S * Fn);

    float m[3][4];
    #pragma unroll
    for (int p = 0; p < 3; ++p)
        #pragma unroll
        for (int j = 0; j < 4; ++j) m[p][j] = NEG;

    if (t < NT) {
        // element j sits in row-in-chunk rj; global s = 4g + rj.
        // s < e  <=>  4g < e - rj
        int a1[4], a2[4];
        #pragma unroll
        for (int j = 0; j < 4; ++j) {
            const int rj = (4 * t + j) / Fn;     // 0..3, thread-constant
            a1[j] = e1 - rj;
            a2[j] = e2 - rj;
        }
        const float* p0 = base + 4 * t;          // 16B aligned

        #pragma unroll 8
        for (int g = 0; g < NCH; ++g) {
            const f32x4 v = *(const f32x4*)(p0 + (size_t)g * CF);  // plain load: L2/L3 cacheable
            const int s4 = 4 * g;
            #pragma unroll
            for (int j = 0; j < 4; ++j) {
                const float vj = v[j];
                const bool c1 = s4 < a1[j];      // piece 0
                const bool c2 = s4 < a2[j];      // piece 0 or 1
                m[0][j] = fmaxf(m[0][j], c1 ? vj : NEG);
                m[1][j] = fmaxf(m[1][j], c2 ? (c1 ? NEG : vj) : NEG);
                m[2][j] = fmaxf(m[2][j], c2 ? NEG : vj);
            }
        }
    }

    // combine the 4 row-parities per filter: scatter to LDS by flat slot,
    // then filter f = max over slots {f, f+230, f+460, f+690}.
    __shared__ float lds[3][CF];
    if (t < NT) {
        #pragma unroll
        for (int p = 0; p < 3; ++p) {
            lds[p][4 * t + 0] = m[p][0];
            lds[p][4 * t + 1] = m[p][1];
            lds[p][4 * t + 2] = m[p][2];
            lds[p][4 * t + 3] = m[p][3];
        }
    }
    __syncthreads();
    if (t < Fn) {
        float* ob = out + (size_t)b * (3 * Fn);
        #pragma unroll
        for (int p = 0; p < 3; ++p) {
            const float mm = fmaxf(fmaxf(lds[p][t],          lds[p][t + Fn]),
                                   fmaxf(lds[p][t + 2 * Fn], lds[p][t + 3 * Fn]));
            __builtin_nontemporal_store(mm, ob + p * Fn + t);
        }
    }
}

extern "C" void kernel_launch(void* const* d_in, const int* in_sizes, int n_in,
                              void* d_out, int out_size, void* d_ws, size_t ws_size,
                              hipStream_t stream)
{
    const float* conv = (const float*)d_in[0];
    const int*   pos  = (const int*)d_in[1];
    float*       out  = (float*)d_out;

    const int B = in_sizes[0] / (S * Fn);   // 2048
    pmax_kernel<<<B, 256, 0, stream>>>(conv, pos, out);
}

// Round 6
// 83.187 us; speedup vs baseline: 1.1110x; 1.1110x over previous
//
#include <hip/hip_runtime.h>

// piecewise max-pool: conv [B, S=256, F=230] f32, positions [B,4] i32 -> out [B, 3*230] f32
// Per batch b: e1=pos[b][1], e2=pos[b][3]; max over s-ranges [0,e1), [e1,e2), [e2,S).
//
// R6: R4 structure (nontemporal float4 loads — R5 proved plain cacheable loads cost
// ~11 us via L2/L3 allocation thrash on this zero-reuse 482 MB stream) with the
// unroll axis isolated: 4 -> 8. Everything else identical to R4.
// Mapping: 4 rows = 920 floats = 3680 B (16B-aligned chunk stride); thread t owns
// flat slots [4t,4t+4) of every 4-row chunk -> all loads global_load_dwordx4 nt,
// register accumulation across all 64 chunks; straddlers (t=57,172) handled by
// per-element row thresholds.

constexpr int S   = 256;
constexpr int Fn  = 230;
constexpr int RPC = 4;                 // rows per chunk
constexpr int CF  = Fn * RPC;          // 920 floats per chunk
constexpr int NCH = S / RPC;           // 64 chunks
constexpr int NT  = CF / 4;            // 230 active threads
constexpr float NEG = -1e30f;

typedef float f32x4 __attribute__((ext_vector_type(4)));

__global__ __launch_bounds__(256) void pmax_kernel(
    const float* __restrict__ conv,
    const int*   __restrict__ pos,
    float*       __restrict__ out)
{
    const int b = blockIdx.x;
    const int t = threadIdx.x;
    const int e1 = pos[b * 4 + 1];
    const int e2 = pos[b * 4 + 3];
    const float* base = conv + (size_t)b * (S * Fn);

    float m[3][4];
    #pragma unroll
    for (int p = 0; p < 3; ++p)
        #pragma unroll
        for (int j = 0; j < 4; ++j) m[p][j] = NEG;

    if (t < NT) {
        // element j sits in row-in-chunk rj; global s = 4g + rj.
        // s < e  <=>  4g < e - rj
        int a1[4], a2[4];
        #pragma unroll
        for (int j = 0; j < 4; ++j) {
            const int rj = (4 * t + j) / Fn;     // 0..3, thread-constant
            a1[j] = e1 - rj;
            a2[j] = e2 - rj;
        }
        const float* p0 = base + 4 * t;          // 16B aligned

        #pragma unroll 8
        for (int g = 0; g < NCH; ++g) {
            const f32x4 v = __builtin_nontemporal_load(
                (const f32x4*)(p0 + (size_t)g * CF));
            const int s4 = 4 * g;
            #pragma unroll
            for (int j = 0; j < 4; ++j) {
                const float vj = v[j];
                const bool c1 = s4 < a1[j];      // piece 0
                const bool c2 = s4 < a2[j];      // piece 0 or 1
                m[0][j] = fmaxf(m[0][j], c1 ? vj : NEG);
                m[1][j] = fmaxf(m[1][j], c2 ? (c1 ? NEG : vj) : NEG);
                m[2][j] = fmaxf(m[2][j], c2 ? NEG : vj);
            }
        }
    }

    // combine the 4 row-parities per filter: scatter to LDS by flat slot,
    // then filter f = max over slots {f, f+230, f+460, f+690}.
    __shared__ float lds[3][CF];
    if (t < NT) {
        #pragma unroll
        for (int p = 0; p < 3; ++p) {
            lds[p][4 * t + 0] = m[p][0];
            lds[p][4 * t + 1] = m[p][1];
            lds[p][4 * t + 2] = m[p][2];
            lds[p][4 * t + 3] = m[p][3];
        }
    }
    __syncthreads();
    if (t < Fn) {
        float* ob = out + (size_t)b * (3 * Fn);
        #pragma unroll
        for (int p = 0; p < 3; ++p) {
            const float mm = fmaxf(fmaxf(lds[p][t],          lds[p][t + Fn]),
                                   fmaxf(lds[p][t + 2 * Fn], lds[p][t + 3 * Fn]));
            __builtin_nontemporal_store(mm, ob + p * Fn + t);
        }
    }
}

extern "C" void kernel_launch(void* const* d_in, const int* in_sizes, int n_in,
                              void* d_out, int out_size, void* d_ws, size_t ws_size,
                              hipStream_t stream)
{
    const float* conv = (const float*)d_in[0];
    const int*   pos  = (const int*)d_in[1];
    float*       out  = (float*)d_out;

    const int B = in_sizes[0] / (S * Fn);   // 2048
    pmax_kernel<<<B, 256, 0, stream>>>(conv, pos, out);
}

// Round 7
// 81.958 us; speedup vs baseline: 1.1277x; 1.0150x over previous
//
#include <hip/hip_runtime.h>

// piecewise max-pool: conv [B, S=256, F=230] f32, positions [B,4] i32 -> out [B, 3*230] f32
// Per batch b: e1=pos[b][1], e2=pos[b][3]; max over s-ranges [0,e1), [e1,e2), [e2,S).
//
// FINAL (= R4, the best measured config; R5/R6 A/Bs regressed):
//  - float4 flat-chunk mapping: 4 rows = 920 floats = 3680 B -> 16B-aligned chunk
//    stride; thread t (0..229) owns flat slots [4t,4t+4) of every 4-row chunk, so
//    all loads are global_load_dwordx4 and each thread keeps the same filter slots
//    across all 64 chunks (register accumulation). Straddlers (t=57,172) handled by
//    per-element row-in-chunk thresholds.
//  - NONTEMPORAL loads: zero-reuse 482 MB stream; cacheable loads cost +11 us
//    (L2/L3 allocation thrash, measured R5).
//  - unroll 4 (unroll 8 measured +1.7 us, R6).
//  - branchless piece select vs wave-uniform e1/e2; final 4-way parity combine in LDS.
// Measured: 81.5 us = 5.99 TB/s = 95% of float4-copy ceiling (6.29 TB/s).

constexpr int S   = 256;
constexpr int Fn  = 230;
constexpr int RPC = 4;                 // rows per chunk
constexpr int CF  = Fn * RPC;          // 920 floats per chunk
constexpr int NCH = S / RPC;           // 64 chunks
constexpr int NT  = CF / 4;            // 230 active threads
constexpr float NEG = -1e30f;

typedef float f32x4 __attribute__((ext_vector_type(4)));

__global__ __launch_bounds__(256) void pmax_kernel(
    const float* __restrict__ conv,
    const int*   __restrict__ pos,
    float*       __restrict__ out)
{
    const int b = blockIdx.x;
    const int t = threadIdx.x;
    const int e1 = pos[b * 4 + 1];
    const int e2 = pos[b * 4 + 3];
    const float* base = conv + (size_t)b * (S * Fn);

    float m[3][4];
    #pragma unroll
    for (int p = 0; p < 3; ++p)
        #pragma unroll
        for (int j = 0; j < 4; ++j) m[p][j] = NEG;

    if (t < NT) {
        // element j sits in row-in-chunk rj; global s = 4g + rj.
        // s < e  <=>  4g < e - rj
        int a1[4], a2[4];
        #pragma unroll
        for (int j = 0; j < 4; ++j) {
            const int rj = (4 * t + j) / Fn;     // 0..3, thread-constant
            a1[j] = e1 - rj;
            a2[j] = e2 - rj;
        }
        const float* p0 = base + 4 * t;          // 16B aligned

        #pragma unroll 4
        for (int g = 0; g < NCH; ++g) {
            const f32x4 v = __builtin_nontemporal_load(
                (const f32x4*)(p0 + (size_t)g * CF));
            const int s4 = 4 * g;
            #pragma unroll
            for (int j = 0; j < 4; ++j) {
                const float vj = v[j];
                const bool c1 = s4 < a1[j];      // piece 0
                const bool c2 = s4 < a2[j];      // piece 0 or 1
                m[0][j] = fmaxf(m[0][j], c1 ? vj : NEG);
                m[1][j] = fmaxf(m[1][j], c2 ? (c1 ? NEG : vj) : NEG);
                m[2][j] = fmaxf(m[2][j], c2 ? NEG : vj);
            }
        }
    }

    // combine the 4 row-parities per filter: scatter to LDS by flat slot,
    // then filter f = max over slots {f, f+230, f+460, f+690}.
    __shared__ float lds[3][CF];
    if (t < NT) {
        #pragma unroll
        for (int p = 0; p < 3; ++p) {
            lds[p][4 * t + 0] = m[p][0];
            lds[p][4 * t + 1] = m[p][1];
            lds[p][4 * t + 2] = m[p][2];
            lds[p][4 * t + 3] = m[p][3];
        }
    }
    __syncthreads();
    if (t < Fn) {
        float* ob = out + (size_t)b * (3 * Fn);
        #pragma unroll
        for (int p = 0; p < 3; ++p) {
            const float mm = fmaxf(fmaxf(lds[p][t],          lds[p][t + Fn]),
                                   fmaxf(lds[p][t + 2 * Fn], lds[p][t + 3 * Fn]));
            __builtin_nontemporal_store(mm, ob + p * Fn + t);
        }
    }
}

extern "C" void kernel_launch(void* const* d_in, const int* in_sizes, int n_in,
                              void* d_out, int out_size, void* d_ws, size_t ws_size,
                              hipStream_t stream)
{
    const float* conv = (const float*)d_in[0];
    const int*   pos  = (const int*)d_in[1];
    float*       out  = (float*)d_out;

    const int B = in_sizes[0] / (S * Fn);   // 2048
    pmax_kernel<<<B, 256, 0, stream>>>(conv, pos, out);
}